// Round 3
// baseline (140.977 us; speedup 1.0000x reference)
//
#include <hip/hip_runtime.h>

// SSIM fused: [16,1,1024,1024] fp32, 11-tap separable Gaussian.
// 4 blur channels (a, b, a^2+b^2, a*b) packed as float4 per column in LDS.
// 2 columns/thread; horizontal taps = single ds_read_b128 each, XOR-swizzled
// to stay bank-conflict-free at 2-col stride. Vertical blur in v2f register
// rings (packed fp32 math). Deterministic two-stage reduction -> d_out[0].

typedef float v2f __attribute__((ext_vector_type(2)));

#define W      1024
#define H      1024
#define NIMG   16
#define WS     11
#define HALO   5
#define BX     192                     // threads (3 waves)
#define SPAN   (2*BX)                  // 384 cols covered per block
#define OUT0   6                       // first output rel col (even-aligned)
#define OUTC   (SPAN - 2*OUT0)         // 372 output cols per block
#define ROWS   44                      // output rows per block (multiple of 11)
#define GX     3                       // ceil(W/OUTC)
#define GY     ((H + ROWS - 1)/ROWS)   // 24
#define NBLK   (GX*GY*NIMG)            // 1152

#define CS(c)  ((c) ^ (((c)>>3)&1))    // float4-index swizzle (bijective)

template<bool INT>
__device__ __forceinline__ v2f load2(const float* __restrict__ p, int j, int c)
{
    if (INT) {
        return *(const v2f*)(p + (size_t)j * W + c);
    } else {
        v2f r;
        const bool jok = (j >= 0) && (j < H);
        r.x = (jok && (unsigned)(c)     < W) ? p[(size_t)j * W + c    ] : 0.0f;
        r.y = (jok && (unsigned)(c + 1) < W) ? p[(size_t)j * W + c + 1] : 0.0f;
        return r;
    }
}

template<bool INT>
__device__ __forceinline__ float tile_loop(const float* __restrict__ p1,
                                           const float* __restrict__ p2,
                                           const float* __restrict__ w,
                                           int cg, int r0, int t,
                                           float4 (*sRow)[SPAN])
{
    // register rings: raw a, b and products q=a^2+b^2, p=a*b (2 cols packed)
    v2f ra[WS], rb[WS], rq[WS], rp[WS];

#pragma unroll
    for (int k = 0; k < WS - 1; ++k) {
        v2f a = load2<INT>(p1, r0 - HALO + k, cg);
        v2f b = load2<INT>(p2, r0 - HALO + k, cg);
        ra[k + 1] = a; rb[k + 1] = b;
        rq[k + 1] = a * a + b * b;
        rp[k + 1] = a * b;
    }

    const bool outT = (t >= OUT0 / 2) && (t < (SPAN - OUT0) / 2);   // [3,189)
    const int  cl   = 2 * t;                                        // rel col of out0
    float tsum = 0.0f;

#pragma unroll 11
    for (int rr = 0; rr < ROWS; ++rr) {
#pragma unroll
        for (int k = 0; k < WS - 1; ++k) {
            ra[k] = ra[k + 1]; rb[k] = rb[k + 1];
            rq[k] = rq[k + 1]; rp[k] = rp[k + 1];
        }
        {
            v2f a = load2<INT>(p1, r0 + rr + HALO, cg);
            v2f b = load2<INT>(p2, r0 + rr + HALO, cg);
            ra[WS - 1] = a; rb[WS - 1] = b;
            rq[WS - 1] = a * a + b * b;
            rp[WS - 1] = a * b;
        }

        // vertical blur, Gaussian symmetry (w[k] == w[10-k]), packed fp32
        v2f vA = w[5] * ra[5], vB = w[5] * rb[5];
        v2f vQ = w[5] * rq[5], vP = w[5] * rp[5];
#pragma unroll
        for (int k = 0; k < 5; ++k) {
            vA += w[k] * (ra[k] + ra[10 - k]);
            vB += w[k] * (rb[k] + rb[10 - k]);
            vQ += w[k] * (rq[k] + rq[10 - k]);
            vP += w[k] * (rp[k] + rp[10 - k]);
        }

        float4* row = sRow[rr & 1];
        row[CS(cl)    ] = make_float4(vA.x, vB.x, vQ.x, vP.x);
        row[CS(cl + 1)] = make_float4(vA.y, vB.y, vQ.y, vP.y);
        __syncthreads();

        if (outT && (INT || (r0 + rr < H))) {
            float m1a = 0.f, m2a = 0.f, qa = 0.f, pa = 0.f;
            float m1b = 0.f, m2b = 0.f, qb = 0.f, pb = 0.f;
            {
                float4 u = row[CS(cl - 5)];
                m1a = fmaf(w[0], u.x, m1a); m2a = fmaf(w[0], u.y, m2a);
                qa  = fmaf(w[0], u.z, qa ); pa  = fmaf(w[0], u.w, pa );
            }
#pragma unroll
            for (int k = 1; k <= 10; ++k) {
                float4 u = row[CS(cl - 5 + k)];
                m1a = fmaf(w[k],     u.x, m1a); m2a = fmaf(w[k],     u.y, m2a);
                qa  = fmaf(w[k],     u.z, qa ); pa  = fmaf(w[k],     u.w, pa );
                m1b = fmaf(w[k - 1], u.x, m1b); m2b = fmaf(w[k - 1], u.y, m2b);
                qb  = fmaf(w[k - 1], u.z, qb ); pb  = fmaf(w[k - 1], u.w, pb );
            }
            {
                float4 u = row[CS(cl + 6)];
                m1b = fmaf(w[10], u.x, m1b); m2b = fmaf(w[10], u.y, m2b);
                qb  = fmaf(w[10], u.z, qb ); pb  = fmaf(w[10], u.w, pb );
            }

            const float C1f = 0.0001f, C2f = 0.0009f;
            if (INT || (cg < W)) {
                const float mu12 = m1a * m2a, m1s = m1a * m1a, m2s = m2a * m2a;
                const float s12 = pa - mu12;
                const float ssq = qa - m1s - m2s;            // sigma1^2+sigma2^2
                const float num = (2.f * mu12 + C1f) * (2.f * s12 + C2f);
                const float den = (m1s + m2s + C1f) * (ssq + C2f);
                tsum += num * __builtin_amdgcn_rcpf(den);
            }
            if (INT || (cg + 1 < W)) {
                const float mu12 = m1b * m2b, m1s = m1b * m1b, m2s = m2b * m2b;
                const float s12 = pb - mu12;
                const float ssq = qb - m1s - m2s;
                const float num = (2.f * mu12 + C1f) * (2.f * s12 + C2f);
                const float den = (m1s + m2s + C1f) * (ssq + C2f);
                tsum += num * __builtin_amdgcn_rcpf(den);
            }
        }
    }
    return tsum;
}

__global__ __launch_bounds__(BX) void ssim_main(const float* __restrict__ img1,
                                                const float* __restrict__ img2,
                                                const float* __restrict__ win,
                                                float* __restrict__ partials)
{
    __shared__ float4 sRow[2][SPAN];

    const int t     = threadIdx.x;
    const int n     = blockIdx.z;
    const int bx    = blockIdx.x;
    const int gy    = blockIdx.y;
    const int cbase = bx * OUTC - OUT0;
    const int cg    = cbase + 2 * t;
    const int r0    = gy * ROWS;

    const float* __restrict__ p1 = img1 + (size_t)n * (size_t)(W * H);
    const float* __restrict__ p2 = img2 + (size_t)n * (size_t)(W * H);

    float w[WS];
#pragma unroll
    for (int k = 0; k < WS; ++k)
        w[k] = __int_as_float(__builtin_amdgcn_readfirstlane(__float_as_int(win[k])));

    const bool interior = (cbase >= 0) && (cbase + SPAN <= W) &&
                          (r0 >= HALO) && (r0 + ROWS + HALO <= H);

    float tsum = interior ? tile_loop<true >(p1, p2, w, cg, r0, t, sRow)
                          : tile_loop<false>(p1, p2, w, cg, r0, t, sRow);

    // block reduction (3 waves of 64)
#pragma unroll
    for (int off = 32; off > 0; off >>= 1)
        tsum += __shfl_down(tsum, off, 64);

    __shared__ float wsum[BX / 64];
    if ((t & 63) == 0) wsum[t >> 6] = tsum;
    __syncthreads();
    if (t == 0) {
        const float s = wsum[0] + wsum[1] + wsum[2];
        partials[((size_t)n * GY + gy) * GX + bx] = s;
    }
}

__global__ __launch_bounds__(256) void ssim_finalize(const float* __restrict__ partials,
                                                     float* __restrict__ out)
{
    double s = 0.0;
    for (int i = threadIdx.x; i < NBLK; i += 256) s += (double)partials[i];
#pragma unroll
    for (int off = 32; off > 0; off >>= 1)
        s += __shfl_down(s, off, 64);

    __shared__ double ws[4];
    if ((threadIdx.x & 63) == 0) ws[threadIdx.x >> 6] = s;
    __syncthreads();
    if (threadIdx.x == 0) {
        const double tt = ws[0] + ws[1] + ws[2] + ws[3];
        out[0] = (float)(tt / (double)((size_t)NIMG * W * H));
    }
}

extern "C" void kernel_launch(void* const* d_in, const int* in_sizes, int n_in,
                              void* d_out, int out_size, void* d_ws, size_t ws_size,
                              hipStream_t stream)
{
    const float* img1 = (const float*)d_in[0];
    const float* img2 = (const float*)d_in[1];
    const float* win  = (const float*)d_in[2];
    float* partials   = (float*)d_ws;
    float* out        = (float*)d_out;

    dim3 grid(GX, GY, NIMG);
    dim3 block(BX);
    ssim_main<<<grid, block, 0, stream>>>(img1, img2, win, partials);
    ssim_finalize<<<1, 256, 0, stream>>>(partials, out);
}

// Round 4
// 91.295 us; speedup vs baseline: 1.5442x; 1.5442x over previous
//
#include <hip/hip_runtime.h>

// SSIM fused: [16,1,1024,1024] fp32, 11-tap separable Gaussian.
// V-phase: 1 col/thread, register ring of 11 rows x packed float4 channels
//          {a, b, a^2+b^2, a*b}; one ds_write_b128 per pixel (stride-1 lanes).
// H-phase: 8-col runs per thread; 18 swizzled ds_read_b128 -> 8 outputs in
//          register sliding-window accumulators (2.25 LDS reads/px).
// Swizzle s^((s>>3)&7) spreads the stride-8 read pattern across banks.
// Deterministic two-stage reduction -> d_out[0].

typedef float f4 __attribute__((ext_vector_type(4)));

#define W      1024
#define H      1024
#define NIMG   16
#define HALO   5
#define BX     128                 // threads = LDS slots (input cols) per block
#define OUTW   118                 // output cols per block
#define RPS    8                   // rows per stage
#define NSTG   8                   // stages per block
#define TH     (RPS*NSTG)          // 64 output rows per block
#define GX     9                   // ceil(1024/118)
#define GY     (H/TH)              // 16
#define NRUN   15                  // runs 0..13: 8 outs; run 14: S0=110, outs 2..7
#define NBLK   (GX*GY*NIMG)        // 2304

__device__ __forceinline__ int swz(int s) { return s ^ ((s >> 3) & 7); }

template<bool INT>
__device__ __forceinline__ f4 load_ch(const float* __restrict__ p1,
                                      const float* __restrict__ p2,
                                      int j, int c, bool cOK)
{
    float a, b;
    if (INT) {
        a = p1[(size_t)j * W + c];
        b = p2[(size_t)j * W + c];
    } else {
        const bool ok = cOK && ((unsigned)j < H);
        a = ok ? p1[(size_t)j * W + c] : 0.0f;
        b = ok ? p2[(size_t)j * W + c] : 0.0f;
    }
    f4 v;
    v.x = a; v.y = b;
    v.z = fmaf(a, a, b * b);
    v.w = a * b;
    return v;
}

template<bool INT>
__device__ float tile(const float* __restrict__ p1,
                      const float* __restrict__ p2,
                      const float* __restrict__ w,
                      int cb, int r0, int t,
                      f4 (*lds)[RPS][BX])
{
    const int  c   = cb + t;                         // this thread's input col
    const bool cOK = INT || ((unsigned)c < W);

    // ring[1..10] <- rows r0-5 .. r0+4 (packed 4 channels)
    f4 ring[11];
#pragma unroll
    for (int k = 0; k < 10; ++k)
        ring[k + 1] = load_ch<INT>(p1, p2, r0 - HALO + k, c, cOK);

    // h-task mapping
    const int  q     = t / NRUN;                     // staged row index
    const int  run   = t - q * NRUN;                 // column run index
    const int  S0    = (run == 14) ? 110 : 8 * run;  // first LDS slot of run
    const bool hT    = (t < RPS * NRUN);             // 120 h-active threads
    const int  wslot = swz(t);                       // v-phase write slot

    float tsum = 0.0f;

    for (int st = 0; st < NSTG; ++st) {
        const int buf = st & 1;

        // ---------- V phase: 8 rows ----------
#pragma unroll
        for (int rr = 0; rr < RPS; ++rr) {
#pragma unroll
            for (int k = 0; k < 10; ++k) ring[k] = ring[k + 1];
            ring[10] = load_ch<INT>(p1, p2, r0 + st * RPS + rr + HALO, c, cOK);

            f4 acc = w[5] * ring[5];
#pragma unroll
            for (int k = 0; k < 5; ++k)
                acc += w[k] * (ring[k] + ring[10 - k]);

            lds[buf][rr][wslot] = acc;
        }
        __syncthreads();

        // ---------- H phase: 120 threads, 8-col runs ----------
        if (hT) {
            f4 o[8] = {};
#pragma unroll
            for (int i = 0; i < 18; ++i) {
                const f4 u = lds[buf][q][swz(S0 + i)];
#pragma unroll
                for (int oo = 0; oo < 8; ++oo) {
                    const int k = i - oo;
                    if (k >= 0 && k < 11)
                        o[oo] += w[k] * u;
                }
            }

            const int rAbs = r0 + st * RPS + q;        // output row (always < H here)
            const int cBase = cb + S0 + HALO;          // abs col of output 0
            const float C1f = 0.0001f, C2f = 0.0009f;
#pragma unroll
            for (int oo = 0; oo < 8; ++oo) {
                // run 14 re-covers cols of run 13 at oo<2 -> skip those
                const bool valid = (oo >= 2 || run < 14) &&
                                   (INT || ((cBase + oo) < W && rAbs < H));
                if (valid) {
                    const float m1 = o[oo].x, m2 = o[oo].y;
                    const float qq = o[oo].z, pp = o[oo].w;
                    const float mu12 = m1 * m2, m1s = m1 * m1, m2s = m2 * m2;
                    const float s12 = pp - mu12;
                    const float ssq = qq - m1s - m2s;
                    const float num = (2.f * mu12 + C1f) * (2.f * s12 + C2f);
                    const float den = (m1s + m2s + C1f) * (ssq + C2f);
                    tsum += num * __builtin_amdgcn_rcpf(den);
                }
            }
        }
    }
    return tsum;
}

__global__ __launch_bounds__(BX) void ssim_main(const float* __restrict__ img1,
                                                const float* __restrict__ img2,
                                                const float* __restrict__ win,
                                                float* __restrict__ partials)
{
    __shared__ f4 lds[2][RPS][BX];

    const int t  = threadIdx.x;
    const int n  = blockIdx.z;
    const int bx = blockIdx.x;
    const int gy = blockIdx.y;
    const int cb = bx * OUTW - HALO;    // input col of LDS slot 0
    const int r0 = gy * TH;

    const float* __restrict__ p1 = img1 + (size_t)n * (size_t)(W * H);
    const float* __restrict__ p2 = img2 + (size_t)n * (size_t)(W * H);

    float w[11];
#pragma unroll
    for (int k = 0; k < 11; ++k)
        w[k] = __int_as_float(__builtin_amdgcn_readfirstlane(__float_as_int(win[k])));

    const bool interior = (cb >= 0) && (cb + BX <= W) &&
                          (r0 - HALO >= 0) && (r0 + TH - 1 + HALO < H);

    float tsum = interior ? tile<true >(p1, p2, w, cb, r0, t, lds)
                          : tile<false>(p1, p2, w, cb, r0, t, lds);

    // block reduction (2 waves of 64)
#pragma unroll
    for (int off = 32; off > 0; off >>= 1)
        tsum += __shfl_down(tsum, off, 64);

    __shared__ float wsum[BX / 64];
    if ((t & 63) == 0) wsum[t >> 6] = tsum;
    __syncthreads();
    if (t == 0)
        partials[((size_t)n * GY + gy) * GX + bx] = wsum[0] + wsum[1];
}

__global__ __launch_bounds__(256) void ssim_finalize(const float* __restrict__ partials,
                                                     float* __restrict__ out)
{
    double s = 0.0;
    for (int i = threadIdx.x; i < NBLK; i += 256) s += (double)partials[i];
#pragma unroll
    for (int off = 32; off > 0; off >>= 1)
        s += __shfl_down(s, off, 64);

    __shared__ double ws[4];
    if ((threadIdx.x & 63) == 0) ws[threadIdx.x >> 6] = s;
    __syncthreads();
    if (threadIdx.x == 0) {
        const double tt = ws[0] + ws[1] + ws[2] + ws[3];
        out[0] = (float)(tt / (double)((size_t)NIMG * W * H));
    }
}

extern "C" void kernel_launch(void* const* d_in, const int* in_sizes, int n_in,
                              void* d_out, int out_size, void* d_ws, size_t ws_size,
                              hipStream_t stream)
{
    const float* img1 = (const float*)d_in[0];
    const float* img2 = (const float*)d_in[1];
    const float* win  = (const float*)d_in[2];
    float* partials   = (float*)d_ws;
    float* out        = (float*)d_out;

    dim3 grid(GX, GY, NIMG);
    dim3 block(BX);
    ssim_main<<<grid, block, 0, stream>>>(img1, img2, win, partials);
    ssim_finalize<<<1, 256, 0, stream>>>(partials, out);
}